// Round 6
// baseline (507.199 us; speedup 1.0000x reference)
//
#include <hip/hip_runtime.h>

#define BATCH 8192
#define FEAT  4096
#define MID   512
#define EMB   256
#define KCODE 512
#define N23   768   // 256 (w2T cols) + 512 (W23 cols)

typedef _Float16 half8 __attribute__((ext_vector_type(8)));
typedef _Float16 half4v __attribute__((ext_vector_type(4)));
typedef float floatx4 __attribute__((ext_vector_type(4)));

// Power-of-2 scales; descaled exactly downstream.
#define SC_X    512.0f
#define SC_W    4096.0f
#define SC_H    512.0f
#define SC_CODE 4096.0f
#define SC_T    4096.0f
#define SC_EMB  4096.0f
#define SC_TM   512.0f
#define DS_G1   (1.0f / (SC_X    * SC_W))   // 2^-21
#define DS_ENC  (1.0f / (SC_H    * SC_W))   // 2^-21
#define DS_S    (1.0f / (SC_H    * SC_T))   // 2^-21
#define DS_T    (1.0f / (SC_CODE * SC_W))   // 2^-24
#define DS_D1   (1.0f / (SC_EMB  * SC_W))
#define DS_D2   (1.0f / (SC_TM   * SC_W))

#define GLD16(gp, lp)                                                          \
    __builtin_amdgcn_global_load_lds(                                          \
        (const __attribute__((address_space(1))) void*)(gp),                   \
        (__attribute__((address_space(3))) void*)(lp), 16, 0, 0)

// ---------------------------------------------------------------------------
// Split-K MFMA GEMM, tile 128x128, BK=32, 4 waves (2x2 of 64x64).
// C = A @ B^T (B pre-split/scaled f16 hi/lo, TRANSPOSED [N][K]).
// NT=3: hi*hi + hi*lo + lo*hi (fp32-equivalent). NT=1: hi only.
// AF32=1: A fp32, split to scaled f16 hi/lo in-register. AF32=0: pre-split.
// A is register ping-pong prefetched: load(k+1) overlaps compute(k), so the
// load latency + split VALU sits under MFMA, not before the barrier.
// B staged via global_load_lds width-16.
// partOut: raw fp32 partials at partOut[ks*M*N + ...]. Else final epilogue.
// swz: 1-D grid, b -> {m_lo=b&7, ks, n, m_hi}: n/k-peers of an M-stripe share
// XCD for L2-shared A (use when A is large). swz=0: 3-D grid (bn, bm, ks).
// Requires Kslice % 64 == 0.
// ---------------------------------------------------------------------------
template<int NT, int AF32>
__global__ __launch_bounds__(256)
void gemm_sk(const float* __restrict__ Af32,
             const _Float16* __restrict__ Ahg, const _Float16* __restrict__ Alg,
             const _Float16* __restrict__ BTh, const _Float16* __restrict__ BTl,
             float aScale,
             float* __restrict__ partOut,
             const float* __restrict__ bias, float descale, int relu,
             float* __restrict__ outF, _Float16* __restrict__ outHi,
             _Float16* __restrict__ outLo, float outScale,
             int M, int N, int K, int lgK, int lgN, int swz)
{
    __shared__ _Float16 AhS[128 * 32];
    __shared__ _Float16 BhS[128 * 32];
    __shared__ _Float16 AlS[NT == 3 ? 128 * 32 : 8];
    __shared__ _Float16 BlS[NT == 3 ? 128 * 32 : 8];

    const int tid  = threadIdx.x;
    const int lane = tid & 63;
    const int wave = tid >> 6;
    const int wm = wave >> 1, wn = wave & 1;
    const int l15  = lane & 15;
    const int quad = lane >> 4;
    const int q8   = quad * 8;

    int bm, bn, ks;
    if (swz) {
        int b = blockIdx.x;
        int mlo = b & 7;
        ks = (b >> 3) & ((1 << lgK) - 1);
        bn = (b >> (3 + lgK)) & ((1 << lgN) - 1);
        bm = ((b >> (3 + lgK + lgN)) << 3) | mlo;
    } else { bn = blockIdx.x; bm = blockIdx.y; ks = blockIdx.z; }
    const int row0 = bm * 128, col0 = bn * 128;
    const int Kslice = K >> lgK;
    const int k0 = ks * Kslice;

    // B staging (GLD16): thread covers 8 f16; two calls cover 128 rows
    const int sr4 = tid >> 2;
    const int sc4 = (tid & 3) * 8;
    const size_t bB0 = (size_t)(col0 + sr4) * K + sc4;
    const size_t bB1 = (size_t)(col0 + 64 + sr4) * K + sc4;
    const int l0 = tid * 8, l1 = 2048 + tid * 8;

    // A register staging: thread covers row tid>>1, 16 elems at (tid&1)*16
    const int sr2 = tid >> 1;
    const int sk2 = (tid & 1) * 16;
    const size_t aOff2 = (size_t)(row0 + sr2) * K + sk2;
    const int lA = sr2 * 32 + sk2;

    floatx4 acc[4][4] = {};
    float4 fa[2][4];
    half8  rah[2][2], ral[2][2];

    auto loadA = [&](int s, int kt) {
        if (AF32) {
            const float* p = Af32 + aOff2 + k0 + kt;
            fa[s][0] = *(const float4*)(p);
            fa[s][1] = *(const float4*)(p + 4);
            fa[s][2] = *(const float4*)(p + 8);
            fa[s][3] = *(const float4*)(p + 12);
        } else {
            const _Float16* p = Ahg + aOff2 + k0 + kt;
            rah[s][0] = *(const half8*)(p);
            rah[s][1] = *(const half8*)(p + 8);
            if (NT == 3) {
                const _Float16* q = Alg + aOff2 + k0 + kt;
                ral[s][0] = *(const half8*)(q);
                ral[s][1] = *(const half8*)(q + 8);
            }
        }
    };

    auto writeA = [&](int s) {
        if (AF32) {
            const float* f = (const float*)&fa[s][0];
            half8 hv0, hv1, lv0, lv1;
            #pragma unroll
            for (int e = 0; e < 8; ++e) {
                float v = f[e] * aScale;
                _Float16 h = (_Float16)v;
                hv0[e] = h; lv0[e] = (_Float16)(v - (float)h);
            }
            #pragma unroll
            for (int e = 0; e < 8; ++e) {
                float v = f[8 + e] * aScale;
                _Float16 h = (_Float16)v;
                hv1[e] = h; lv1[e] = (_Float16)(v - (float)h);
            }
            *(half8*)&AhS[lA] = hv0; *(half8*)&AhS[lA + 8] = hv1;
            if (NT == 3) { *(half8*)&AlS[lA] = lv0; *(half8*)&AlS[lA + 8] = lv1; }
        } else {
            *(half8*)&AhS[lA] = rah[s][0]; *(half8*)&AhS[lA + 8] = rah[s][1];
            if (NT == 3) { *(half8*)&AlS[lA] = ral[s][0]; *(half8*)&AlS[lA + 8] = ral[s][1]; }
        }
    };

    auto stageB = [&](int kt) {
        GLD16(BTh + bB0 + k0 + kt, &BhS[l0]);
        GLD16(BTh + bB1 + k0 + kt, &BhS[l1]);
        if (NT == 3) {
            GLD16(BTl + bB0 + k0 + kt, &BlS[l0]);
            GLD16(BTl + bB1 + k0 + kt, &BlS[l1]);
        }
    };

    auto computeTile = [&]() {
        half8 ah[4], al4[4], bh[4], bl4[4];
        #pragma unroll
        for (int i = 0; i < 4; ++i) {
            int ra = (wm * 64 + i * 16 + l15) * 32 + q8;
            int rb = (wn * 64 + i * 16 + l15) * 32 + q8;
            ah[i] = *(const half8*)&AhS[ra];
            bh[i] = *(const half8*)&BhS[rb];
            if (NT == 3) {
                al4[i] = *(const half8*)&AlS[ra];
                bl4[i] = *(const half8*)&BlS[rb];
            }
        }
        #pragma unroll
        for (int i = 0; i < 4; ++i)
            #pragma unroll
            for (int j = 0; j < 4; ++j) {
                acc[i][j] = __builtin_amdgcn_mfma_f32_16x16x32_f16(ah[i], bh[j], acc[i][j], 0, 0, 0);
                if (NT == 3) {
                    acc[i][j] = __builtin_amdgcn_mfma_f32_16x16x32_f16(ah[i],  bl4[j], acc[i][j], 0, 0, 0);
                    acc[i][j] = __builtin_amdgcn_mfma_f32_16x16x32_f16(al4[i], bh[j],  acc[i][j], 0, 0, 0);
                }
            }
    };

    const int nIter = Kslice / 32;   // even by construction
    loadA(0, 0);
    for (int it = 0; it < nIter; it += 2) {
        // even sub-iter: consume reg-set 0
        writeA(0);
        stageB(it * 32);
        __syncthreads();
        if (it + 1 < nIter) loadA(1, (it + 1) * 32);   // overlaps compute
        computeTile();
        __syncthreads();
        // odd sub-iter: consume reg-set 1
        writeA(1);
        stageB((it + 1) * 32);
        __syncthreads();
        if (it + 2 < nIter) loadA(0, (it + 2) * 32);
        computeTile();
        __syncthreads();
    }

    // Epilogue. C/D layout: col = lane&15, row = quad*4 + reg (verified m89).
    if (partOut) {
        float* po = partOut + (size_t)ks * M * N;
        #pragma unroll
        for (int j = 0; j < 4; ++j) {
            int col = col0 + wn * 64 + j * 16 + l15;
            #pragma unroll
            for (int i = 0; i < 4; ++i)
                #pragma unroll
                for (int t = 0; t < 4; ++t) {
                    int r = row0 + wm * 64 + i * 16 + quad * 4 + t;
                    po[(size_t)r * N + col] = acc[i][j][t];
                }
        }
    } else {
        #pragma unroll
        for (int j = 0; j < 4; ++j) {
            int col = col0 + wn * 64 + j * 16 + l15;
            float bcol = bias ? bias[col] : 0.0f;
            #pragma unroll
            for (int i = 0; i < 4; ++i)
                #pragma unroll
                for (int t = 0; t < 4; ++t) {
                    int r = row0 + wm * 64 + i * 16 + quad * 4 + t;
                    float v = acc[i][j][t] * descale + bcol;
                    if (relu) v = fmaxf(v, 0.0f);
                    size_t o = (size_t)r * N + col;
                    if (outF) outF[o] = v;
                    if (outHi) {
                        float sv = v * outScale;
                        _Float16 h = (_Float16)sv;
                        outHi[o] = h;
                        outLo[o] = (_Float16)(sv - (float)h);
                    }
                }
        }
    }
}

// ---------------------------------------------------------------------------
// Split-K reduce: out = relu( (sum_s part[s]) * descale + bias ) -> f16 hi/lo.
// ---------------------------------------------------------------------------
__global__ __launch_bounds__(256)
void reduce_sk(const float* __restrict__ part, int nSlice, int MN, int N,
               const float* __restrict__ bias, float descale, int relu,
               _Float16* __restrict__ outHi, _Float16* __restrict__ outLo,
               float outScale)
{
    int i = blockIdx.x * 256 + threadIdx.x;
    if (i * 4 >= MN) return;
    float4 s = ((const float4*)part)[i];
    for (int sl = 1; sl < nSlice; ++sl) {
        float4 p = ((const float4*)(part + (size_t)sl * MN))[i];
        s.x += p.x; s.y += p.y; s.z += p.z; s.w += p.w;
    }
    int col = (i * 4) % N;
    float v[4] = {s.x, s.y, s.z, s.w};
    half4v hv, lv;
    #pragma unroll
    for (int e = 0; e < 4; ++e) {
        float t = v[e] * descale + (bias ? bias[col + e] : 0.0f);
        if (relu) t = fmaxf(t, 0.0f);
        float sv = t * outScale;
        _Float16 h = (_Float16)sv;
        hv[e] = h;
        lv[e] = (_Float16)(sv - (float)h);
    }
    ((half4v*)outHi)[i] = hv;
    ((half4v*)outLo)[i] = lv;
}

// ---------------------------------------------------------------------------
// Transpose fp32 [R][C] -> scaled f16 hi/lo [C][R]. 32x32 LDS tiles.
// ---------------------------------------------------------------------------
__global__ __launch_bounds__(256)
void transpose_split(const float* __restrict__ src, _Float16* __restrict__ hi,
                     _Float16* __restrict__ lo, float scale, int R, int C)
{
    __shared__ float t[32][33];
    int tx = threadIdx.x & 31, ty = threadIdx.x >> 5;
    int r0 = blockIdx.y * 32, c0 = blockIdx.x * 32;
    #pragma unroll
    for (int p = 0; p < 4; ++p) {
        int r = ty + p * 8;
        t[r][tx] = src[(size_t)(r0 + r) * C + c0 + tx];
    }
    __syncthreads();
    #pragma unroll
    for (int p = 0; p < 4; ++p) {
        int oc = ty + p * 8;
        float v = t[tx][oc] * scale;
        _Float16 h = (_Float16)v;
        size_t o = (size_t)(c0 + oc) * R + r0 + tx;
        hi[o] = h;
        lo[o] = (_Float16)(v - (float)h);
    }
}

// ---------------------------------------------------------------------------
// Plain (no transpose) fp32 -> scaled f16 hi/lo split. 8 elems/thread.
// ---------------------------------------------------------------------------
__global__ __launch_bounds__(256)
void split_plain(const float* __restrict__ src, _Float16* __restrict__ hi,
                 _Float16* __restrict__ lo, float scale, int n8)
{
    int i = blockIdx.x * 256 + threadIdx.x;
    if (i >= n8) return;
    const float4* s4 = (const float4*)src;
    float4 a = s4[i * 2], b = s4[i * 2 + 1];
    float v[8] = {a.x, a.y, a.z, a.w, b.x, b.y, b.z, b.w};
    half8 hv, lv;
    #pragma unroll
    for (int j = 0; j < 8; ++j) {
        float sv = v[j] * scale;
        _Float16 h = (_Float16)sv;
        hv[j] = h;
        lv[j] = (_Float16)(sv - (float)h);
    }
    ((half8*)hi)[i] = hv;
    ((half8*)lo)[i] = lv;
}

// ---------------------------------------------------------------------------
// Normalize codebook rows (fp32 math) -> scaled f16 hi/lo [K][E].
// Also: out_emb passthrough copy and bias3[c] = dot(b2, cn[c]).
// ---------------------------------------------------------------------------
__global__ __launch_bounds__(256)
void norm_codes(const float* __restrict__ emb, const float* __restrict__ b2,
                _Float16* __restrict__ cnHi, _Float16* __restrict__ cnLo,
                float* __restrict__ outEmb, float* __restrict__ bias3)
{
    int wave = threadIdx.x >> 6;
    int lane = threadIdx.x & 63;
    int c = blockIdx.x * 4 + wave;
    if (c >= KCODE) return;
    const float* er = emb + (size_t)c * EMB;
    float ss = 0.0f, sb = 0.0f;
    #pragma unroll
    for (int k = lane; k < EMB; k += 64) {
        float v = er[k];
        ss += v * v;
        sb += v * b2[k];
        outEmb[(size_t)c * EMB + k] = v;
    }
    #pragma unroll
    for (int off = 32; off > 0; off >>= 1) {
        ss += __shfl_down(ss, off, 64);
        sb += __shfl_down(sb, off, 64);
    }
    ss = __shfl(ss, 0, 64);
    sb = __shfl(sb, 0, 64);
    float inv = 1.0f / (sqrtf(ss) + 1e-12f);
    if (lane == 0) bias3[c] = sb * inv;
    #pragma unroll
    for (int k = lane; k < EMB; k += 64) {
        float v = er[k] * inv * SC_CODE;
        _Float16 h = (_Float16)v;
        cnHi[(size_t)c * EMB + k] = h;
        cnLo[(size_t)c * EMB + k] = (_Float16)(v - (float)h);
    }
}

// ---------------------------------------------------------------------------
// Fused finish: per batch row, from G23 partials [2][BATCH][768]:
//   cols 0-255:  encoded = sum*DS_ENC + b2  -> out_encoded (fp32)
//   cols 256-767: s_c = sum*DS_S + bias3[c] -> argmax (first-index tie-break)
//   -> onehot, vq_feat = emb[best], idx. One wave per row.
// ---------------------------------------------------------------------------
__global__ __launch_bounds__(256)
void finish_vq(const float* __restrict__ part, const float* __restrict__ b2,
               const float* __restrict__ bias3, const float* __restrict__ emb,
               float* __restrict__ outEnc, float* __restrict__ onehot,
               float* __restrict__ vqfeat, int* __restrict__ idxOut)
{
    int wave = threadIdx.x >> 6;
    int lane = threadIdx.x & 63;
    int row = blockIdx.x * 4 + wave;
    if (row >= BATCH) return;

    const float* p0 = part + (size_t)row * N23;
    const float* p1 = part + (size_t)BATCH * N23 + (size_t)row * N23;

    #pragma unroll
    for (int c = lane; c < EMB; c += 64)
        outEnc[(size_t)row * EMB + c] = (p0[c] + p1[c]) * DS_ENC + b2[c];

    float bestV = -3.402823466e+38f;
    int   bestI = 0;
    #pragma unroll
    for (int c = lane; c < KCODE; c += 64) {
        float v = (p0[EMB + c] + p1[EMB + c]) * DS_S + bias3[c];
        if (v > bestV) { bestV = v; bestI = c; }   // ascending c: keeps first max
    }
    #pragma unroll
    for (int off = 32; off > 0; off >>= 1) {
        float ov = __shfl_down(bestV, off, 64);
        int   oi = __shfl_down(bestI, off, 64);
        if (ov > bestV || (ov == bestV && oi < bestI)) { bestV = ov; bestI = oi; }
    }
    bestI = __shfl(bestI, 0, 64);
    if (lane == 0) idxOut[row] = bestI;

    float* oh = onehot + (size_t)row * KCODE;
    #pragma unroll
    for (int c = lane; c < KCODE; c += 64) oh[c] = (c == bestI) ? 1.0f : 0.0f;

    const float* er = emb + (size_t)bestI * EMB;
    float* vr = vqfeat + (size_t)row * EMB;
    #pragma unroll
    for (int c = lane; c < EMB; c += 64) vr[c] = er[c];
}

__global__ __launch_bounds__(256)
void gather_decoded(const float* __restrict__ Dcode, const int* __restrict__ idx,
                    float* __restrict__ out)
{
    int row = blockIdx.x;
    int k = idx[row];
    const float4* src = (const float4*)(Dcode + (size_t)k * FEAT);
    float4* dst = (float4*)(out + (size_t)row * FEAT);
    #pragma unroll
    for (int i = threadIdx.x; i < FEAT / 4; i += 256) dst[i] = src[i];
}

// ---------------------------------------------------------------------------
extern "C" void kernel_launch(void* const* d_in, const int* in_sizes, int n_in,
                              void* d_out, int out_size, void* d_ws, size_t ws_size,
                              hipStream_t stream)
{
    const float* x      = (const float*)d_in[0];
    const float* enc_w1 = (const float*)d_in[1];
    const float* enc_b1 = (const float*)d_in[2];
    const float* enc_w2 = (const float*)d_in[3];
    const float* enc_b2 = (const float*)d_in[4];
    const float* emb    = (const float*)d_in[5];
    const float* dec_w1 = (const float*)d_in[6];
    const float* dec_b1 = (const float*)d_in[7];
    const float* dec_w2 = (const float*)d_in[8];
    const float* dec_b2 = (const float*)d_in[9];

    float* out = (float*)d_out;
    float* out_encoded = out;
    float* out_vqfeat  = out + (size_t)BATCH * EMB;
    float* out_onehot  = out + (size_t)2 * BATCH * EMB;
    float* out_decoded = out + (size_t)2 * BATCH * EMB + (size_t)BATCH * KCODE;
    float* out_emb     = out_decoded + (size_t)BATCH * FEAT;

    // ------- workspace layout (~110 MB) -------
    char* w = (char*)d_ws;
    _Float16* w1T_hi = (_Float16*)w;  w += (size_t)FEAT * MID * 2;
    _Float16* w1T_lo = (_Float16*)w;  w += (size_t)FEAT * MID * 2;
    _Float16* wd2T_hi= (_Float16*)w;  w += (size_t)FEAT * MID * 2;
    _Float16* wd2T_lo= (_Float16*)w;  w += (size_t)FEAT * MID * 2;
    _Float16* w2s_hi = (_Float16*)w;  w += (size_t)MID * EMB * 2;
    _Float16* w2s_lo = (_Float16*)w;  w += (size_t)MID * EMB * 2;
    _Float16* wd1T_hi= (_Float16*)w;  w += (size_t)MID * EMB * 2;
    _Float16* wd1T_lo= (_Float16*)w;  w += (size_t)MID * EMB * 2;
    _Float16* h_hi   = (_Float16*)w;  w += (size_t)BATCH * MID * 2;
    _Float16* h_lo   = (_Float16*)w;  w += (size_t)BATCH * MID * 2;
    _Float16* cn_hi  = (_Float16*)w;  w += (size_t)KCODE * EMB * 2;
    _Float16* cn_lo  = (_Float16*)w;  w += (size_t)KCODE * EMB * 2;
    _Float16* B23_hi = (_Float16*)w;  w += (size_t)N23 * MID * 2;   // rows 0-255: w2T; 256-767: W23T
    _Float16* B23_lo = (_Float16*)w;  w += (size_t)N23 * MID * 2;
    _Float16* tm_hi  = (_Float16*)w;  w += (size_t)KCODE * MID * 2;
    _Float16* tm_lo  = (_Float16*)w;  w += (size_t)KCODE * MID * 2;
    float*    bias3  = (float*)w;     w += (size_t)KCODE * 4;
    float*    Dc     = (float*)w;     w += (size_t)KCODE * FEAT * 4;
    float*    scr    = (float*)w;     w += (size_t)4 * BATCH * MID * 4;  // 64 MB (G1: 4 slices; G23: 2x8192x768 = 48 MB)
    int*      idx    = (int*)w;

    // --- prep ---
    transpose_split<<<dim3(MID / 32, FEAT / 32), dim3(256), 0, stream>>>(
        enc_w1, w1T_hi, w1T_lo, SC_W, FEAT, MID);
    transpose_split<<<dim3(EMB / 32, MID / 32), dim3(256), 0, stream>>>(
        enc_w2, B23_hi, B23_lo, SC_W, MID, EMB);      // B23 rows 0-255 = w2T
    transpose_split<<<dim3(MID / 32, EMB / 32), dim3(256), 0, stream>>>(
        dec_w1, wd1T_hi, wd1T_lo, SC_W, EMB, MID);
    transpose_split<<<dim3(FEAT / 32, MID / 32), dim3(256), 0, stream>>>(
        dec_w2, wd2T_hi, wd2T_lo, SC_W, MID, FEAT);
    split_plain<<<dim3(MID * EMB / 8 / 256), dim3(256), 0, stream>>>(
        enc_w2, w2s_hi, w2s_lo, SC_W, MID * EMB / 8);
    norm_codes<<<dim3(KCODE / 4), dim3(256), 0, stream>>>(
        emb, enc_b2, cn_hi, cn_lo, out_emb, bias3);

    // --- T-gemm: W23T[c][m] = dot(cn[c], w2[m,:]) -> B23 rows 256-767 (split)
    gemm_sk<3, 0><<<dim3(MID / 128, KCODE / 128, 1), dim3(256), 0, stream>>>(
        nullptr, cn_hi, cn_lo, w2s_hi, w2s_lo, 0.0f,
        nullptr, nullptr, DS_T, 0,
        nullptr, B23_hi + (size_t)EMB * MID, B23_lo + (size_t)EMB * MID, SC_T,
        KCODE, MID, EMB, 0, 0, 0);

    // --- G1: x @ w1 partials; split-K=4, 1024 blocks (4/CU), swizzled
    gemm_sk<3, 1><<<dim3(1024), dim3(256), 0, stream>>>(
        x, nullptr, nullptr, w1T_hi, w1T_lo, SC_X,
        scr, nullptr, 0.0f, 0, nullptr, nullptr, nullptr, 0.0f,
        BATCH, MID, FEAT, 2, 2, 1);
    // red1: h = relu(sum * DS_G1 + b1) -> h hi/lo
    reduce_sk<<<dim3(BATCH * MID / 4 / 256), dim3(256), 0, stream>>>(
        scr, 4, BATCH * MID, MID, enc_b1, DS_G1, 1, h_hi, h_lo, SC_H);

    // --- G23: h @ B23^T partials (encoded cols 0-255, S cols 256-767);
    //     split-K=2, grid (6,64,2) = 768 blocks (3/CU)
    gemm_sk<3, 0><<<dim3(N23 / 128, BATCH / 128, 2), dim3(256), 0, stream>>>(
        nullptr, h_hi, h_lo, B23_hi, B23_lo, 0.0f,
        scr, nullptr, 0.0f, 0, nullptr, nullptr, nullptr, 0.0f,
        BATCH, N23, MID, 1, 0, 0);

    // --- finish: reduce -> encoded; reduce+bias3 -> argmax -> onehot/vqfeat/idx
    finish_vq<<<dim3(BATCH / 4), dim3(256), 0, stream>>>(
        scr, enc_b2, bias3, emb, out_encoded, out_onehot, out_vqfeat, idx);

    // --- decoder on codebook only (512 distinct rows), 1-term f16
    gemm_sk<1, 1><<<dim3(MID / 128, KCODE / 128, 1), dim3(256), 0, stream>>>(
        emb, nullptr, nullptr, wd1T_hi, wd1T_lo, SC_EMB,
        nullptr, dec_b1, DS_D1, 1, nullptr, tm_hi, tm_lo, SC_TM,
        KCODE, MID, EMB, 0, 0, 0);
    gemm_sk<1, 0><<<dim3(FEAT / 128, KCODE / 128, 1), dim3(256), 0, stream>>>(
        nullptr, tm_hi, tm_lo, wd2T_hi, wd2T_lo, 0.0f,
        nullptr, dec_b2, DS_D2, 1, Dc, nullptr, nullptr, 0.0f,
        KCODE, FEAT, MID, 0, 0, 0);

    // --- decoded[i] = Dcode[idx[i]]
    gather_decoded<<<dim3(BATCH), dim3(256), 0, stream>>>(Dc, idx, out_decoded);
}